// Round 8
// baseline (206.158 us; speedup 1.0000x reference)
//
#include <hip/hip_runtime.h>
#include <stdint.h>

#define NB 200000
#define BB 4
#define GG 64
#define MAXPOS 128
#define BATCH 256
#define KPT 2                      // anchors per thread in K1
#define CH 512                     // anchors per K1 block (256 thr * KPT)
#define NCH ((NB + CH - 1) / CH)   // 391
#define REPS 4                     // probe-kernel serial repetitions

// thresholds folded: inter - t*u >= 0  <=>  ((1+t)/t)*inter - (a1+ga) >= 0
#define CP (1.7f / 0.7f)
#define CN (1.3f / 0.3f)

// ---------------- K1: per-anchor threshold flags + per-chunk counts (r4 exact) ----------------
__global__ __launch_bounds__(256) void rpn_flags_kernel(
        const float* __restrict__ anchors, const float* __restrict__ gt,
        uint8_t* __restrict__ flags, uint32_t* __restrict__ chunkCnt) {
    int b = blockIdx.y;
    int tid = threadIdx.x, lane = tid & 63, wid = tid >> 6;
    __shared__ __align__(16) float4 sG[GG];
    if (tid < GG) sG[tid] = ((const float4*)gt)[b * GG + tid];
    __syncthreads();

    int base = blockIdx.x * CH + tid;          // anchor for k=0; k strides by 256
    float4 a[KPT];
    float na1[KPT], mp[KPT], mn[KPT];
    #pragma unroll
    for (int k = 0; k < KPT; ++k) {
        int i = base + k * 256;
        a[k] = (i < NB) ? ((const float4*)anchors)[(size_t)b * NB + i]
                        : make_float4(0.f, 0.f, 0.f, 0.f);
        na1[k] = -((a[k].z - a[k].x) * (a[k].w - a[k].y));
        mp[k] = -1.0f; mn[k] = -1.0f;
    }
    #pragma unroll 8
    for (int g = 0; g < GG; ++g) {
        float4 c = sG[g];                       // broadcast ds_read_b128
        float ga = (c.z - c.x) * (c.w - c.y);
        #pragma unroll
        for (int k = 0; k < KPT; ++k) {
            float w = fmaxf(fminf(a[k].z, c.z) - fmaxf(a[k].x, c.x), 0.0f);
            float h = fmaxf(fminf(a[k].w, c.w) - fmaxf(a[k].y, c.y), 0.0f);
            float inter = w * h;
            float ns = na1[k] - ga;
            mp[k] = fmaxf(mp[k], __builtin_fmaf(CP, inter, ns));
            mn[k] = fmaxf(mn[k], __builtin_fmaf(CN, inter, ns));
        }
    }
    uint32_t pn = 0;
    #pragma unroll
    for (int k = 0; k < KPT; ++k) {
        int i = base + k * 256;
        bool valid = i < NB;
        bool p = valid && (mp[k] >= 0.0f);
        bool n = valid && (mn[k] < 0.0f);
        if (valid) flags[(size_t)b * NB + i] = (uint8_t)((p ? 1 : 0) | (n ? 2 : 0));
        pn += (p ? 1u : 0u) + (n ? 0x10000u : 0u);
    }
    for (int off = 32; off > 0; off >>= 1) pn += __shfl_down(pn, off);
    __shared__ uint32_t wSum[4];
    if (lane == 0) wSum[wid] = pn;
    __syncthreads();
    if (tid == 0)
        chunkCnt[b * NCH + blockIdx.x] = wSum[0] + wSum[1] + wSum[2] + wSum[3];
}

// ---------------- probe: exact K1 clone, REPS serial repetitions ----------------
__global__ __launch_bounds__(256) void rpn_probe_full(
        const float* __restrict__ anchors, const float* __restrict__ gt,
        uint8_t* __restrict__ flags, uint32_t* __restrict__ chunkCnt) {
    int b = blockIdx.y;
    int tid = threadIdx.x, lane = tid & 63, wid = tid >> 6;
    __shared__ __align__(16) float4 sG[GG];
    __shared__ uint32_t wSum[4];
    if (tid < GG) sG[tid] = ((const float4*)gt)[b * GG + tid];
    __syncthreads();
    for (int r = 0; r < REPS; ++r) {
        int base = blockIdx.x * CH + tid + ((r & 1) << 7);   // perturb addr per rep
        float4 a[KPT];
        float na1[KPT], mp[KPT], mn[KPT];
        #pragma unroll
        for (int k = 0; k < KPT; ++k) {
            int i = base + k * 256;
            a[k] = (i < NB) ? ((const float4*)anchors)[(size_t)b * NB + i]
                            : make_float4(0.f, 0.f, 0.f, 0.f);
            na1[k] = -((a[k].z - a[k].x) * (a[k].w - a[k].y));
            mp[k] = -1.0f; mn[k] = -1.0f;
        }
        #pragma unroll 8
        for (int g = 0; g < GG; ++g) {
            float4 c = sG[g];
            float ga = (c.z - c.x) * (c.w - c.y);
            #pragma unroll
            for (int k = 0; k < KPT; ++k) {
                float w = fmaxf(fminf(a[k].z, c.z) - fmaxf(a[k].x, c.x), 0.0f);
                float h = fmaxf(fminf(a[k].w, c.w) - fmaxf(a[k].y, c.y), 0.0f);
                float inter = w * h;
                float ns = na1[k] - ga;
                mp[k] = fmaxf(mp[k], __builtin_fmaf(CP, inter, ns));
                mn[k] = fmaxf(mn[k], __builtin_fmaf(CN, inter, ns));
            }
        }
        uint32_t pn = 0;
        #pragma unroll
        for (int k = 0; k < KPT; ++k) {
            int i = base + k * 256;
            bool valid = i < NB;
            bool p = valid && (mp[k] >= 0.0f);
            bool n = valid && (mn[k] < 0.0f);
            if (valid) flags[(size_t)b * NB + i] = (uint8_t)((p ? 1 : 0) | (n ? 2 : 0));
            pn += (p ? 1u : 0u) + (n ? 0x10000u : 0u);
        }
        for (int off = 32; off > 0; off >>= 1) pn += __shfl_down(pn, off);
        if (lane == 0) wSum[wid] = pn;
        __syncthreads();
        if (tid == 0)
            chunkCnt[b * NCH + blockIdx.x] = wSum[0] + wSum[1] + wSum[2] + wSum[3];
        __syncthreads();
    }
}

// ---------------- probe: compute path only (synthesized anchors, no global anchor loads) ----------------
__global__ __launch_bounds__(256) void rpn_probe_cmp(
        const float* __restrict__ gt,
        uint8_t* __restrict__ flags, uint32_t* __restrict__ chunkCnt) {
    int b = blockIdx.y;
    int tid = threadIdx.x, lane = tid & 63, wid = tid >> 6;
    __shared__ __align__(16) float4 sG[GG];
    __shared__ uint32_t wSum[4];
    if (tid < GG) sG[tid] = ((const float4*)gt)[b * GG + tid];
    __syncthreads();
    for (int r = 0; r < REPS; ++r) {
        int base = blockIdx.x * CH + tid + ((r & 1) << 7);
        float4 a[KPT];
        float na1[KPT], mp[KPT], mn[KPT];
        #pragma unroll
        for (int k = 0; k < KPT; ++k) {
            int i = base + k * 256;
            float fx = (float)((i * 37) & 1023);
            float fy = (float)((i * 53) & 1023);
            a[k] = make_float4(fx, fy, fx + 48.0f, fy + 80.0f);
            na1[k] = -((a[k].z - a[k].x) * (a[k].w - a[k].y));
            mp[k] = -1.0f; mn[k] = -1.0f;
        }
        #pragma unroll 8
        for (int g = 0; g < GG; ++g) {
            float4 c = sG[g];
            float ga = (c.z - c.x) * (c.w - c.y);
            #pragma unroll
            for (int k = 0; k < KPT; ++k) {
                float w = fmaxf(fminf(a[k].z, c.z) - fmaxf(a[k].x, c.x), 0.0f);
                float h = fmaxf(fminf(a[k].w, c.w) - fmaxf(a[k].y, c.y), 0.0f);
                float inter = w * h;
                float ns = na1[k] - ga;
                mp[k] = fmaxf(mp[k], __builtin_fmaf(CP, inter, ns));
                mn[k] = fmaxf(mn[k], __builtin_fmaf(CN, inter, ns));
            }
        }
        uint32_t pn = 0;
        #pragma unroll
        for (int k = 0; k < KPT; ++k) {
            int i = base + k * 256;
            bool valid = i < NB;
            bool p = valid && (mp[k] >= 0.0f);
            bool n = valid && (mn[k] < 0.0f);
            if (valid) flags[(size_t)b * NB + i] = (uint8_t)((p ? 1 : 0) | (n ? 2 : 0));
            pn += (p ? 1u : 0u) + (n ? 0x10000u : 0u);
        }
        for (int off = 32; off > 0; off >>= 1) pn += __shfl_down(pn, off);
        if (lane == 0) wSum[wid] = pn;
        __syncthreads();
        if (tid == 0)
            chunkCnt[b * NCH + blockIdx.x] = wSum[0] + wSum[1] + wSum[2] + wSum[3];
        __syncthreads();
    }
}

// ---------------- probe: memory path only (loads + stores, no IoU loop) ----------------
__global__ __launch_bounds__(256) void rpn_probe_mem(
        const float* __restrict__ anchors, const float* __restrict__ gt,
        uint8_t* __restrict__ flags, uint32_t* __restrict__ chunkCnt) {
    int b = blockIdx.y;
    int tid = threadIdx.x, lane = tid & 63, wid = tid >> 6;
    __shared__ __align__(16) float4 sG[GG];
    __shared__ uint32_t wSum[4];
    if (tid < GG) sG[tid] = ((const float4*)gt)[b * GG + tid];
    __syncthreads();
    for (int r = 0; r < REPS; ++r) {
        int base = blockIdx.x * CH + tid + ((r & 1) << 7);
        uint32_t pn = 0;
        #pragma unroll
        for (int k = 0; k < KPT; ++k) {
            int i = base + k * 256;
            bool valid = i < NB;
            float4 a = valid ? ((const float4*)anchors)[(size_t)b * NB + i]
                             : make_float4(0.f, 0.f, 0.f, 0.f);
            float s = (a.x + a.y) + (a.z + a.w) + sG[tid & (GG - 1)].x;
            bool p = valid && (s >= 100.0f);
            bool n = valid && (s < 3000.0f);
            if (valid) flags[(size_t)b * NB + i] = (uint8_t)((p ? 1 : 0) | (n ? 2 : 0));
            pn += (p ? 1u : 0u) + (n ? 0x10000u : 0u);
        }
        for (int off = 32; off > 0; off >>= 1) pn += __shfl_down(pn, off);
        if (lane == 0) wSum[wid] = pn;
        __syncthreads();
        if (tid == 0)
            chunkCnt[b * NCH + blockIdx.x] = wSum[0] + wSum[1] + wSum[2] + wSum[3];
        __syncthreads();
    }
}

// ---------------- K2: scan chunk counts, parallel ordered selection, loss (r4 exact) ----------------
__global__ __launch_bounds__(1024) void rpn_select_kernel(
        const uint8_t* __restrict__ flags,
        const float* __restrict__ logits, const float* __restrict__ breg,
        const float* __restrict__ anchors, const float* __restrict__ gt,
        const uint32_t* __restrict__ chunkCnt,
        float* __restrict__ partial) {
    int b = blockIdx.x;
    const uint8_t* __restrict__ F = flags + (size_t)b * NB;
    __shared__ __align__(16) float4 sG[GG];
    __shared__ int basP[NCH], basN[NCH];
    __shared__ unsigned long long wTot[16];
    __shared__ int sNumPos, sNumNeg;
    __shared__ int selPos[MAXPOS];
    __shared__ int selNeg[BATCH];
    __shared__ float sB, sS;
    int tid = threadIdx.x, lane = tid & 63, wid = tid >> 6;

    if (tid < GG) sG[tid] = ((const float4*)gt)[b * GG + tid];

    unsigned long long e = 0ULL;
    if (tid < NCH) {
        uint32_t c = chunkCnt[b * NCH + tid];
        e = (unsigned long long)(c & 0xFFFFu) | ((unsigned long long)(c >> 16) << 32);
    }
    unsigned long long inc = e;
    for (int off = 1; off < 64; off <<= 1) {
        unsigned long long v = __shfl_up(inc, off);
        if (lane >= off) inc += v;
    }
    if (lane == 63) wTot[wid] = inc;
    if (tid == 0) { sB = 0.0f; sS = 0.0f; }
    __syncthreads();
    if (wid == 0) {
        unsigned long long w = (lane < 16) ? wTot[lane] : 0ULL;
        unsigned long long winc = w;
        for (int off = 1; off < 16; off <<= 1) {
            unsigned long long v = __shfl_up(winc, off);
            if (lane >= off) winc += v;
        }
        if (lane < 16) wTot[lane] = winc - w;
        if (lane == 15) {
            int tp = (int)(winc & 0xFFFFFFFFULL);
            int tn = (int)(winc >> 32);
            int np_ = min(tp, MAXPOS);
            sNumPos = np_;
            sNumNeg = min(tn, BATCH - np_);
        }
    }
    __syncthreads();
    if (tid < NCH) {
        unsigned long long ex = wTot[wid] + (inc - e);
        basP[tid] = (int)(ex & 0xFFFFFFFFULL);
        basN[tid] = (int)(ex >> 32);
    }
    __syncthreads();
    int numPos = sNumPos, numNeg = sNumNeg;

    for (int c = wid; c < NCH; c += 16) {
        int bp = basP[c], bn = basN[c];
        if (bp >= numPos && bn >= numNeg) break;
        int offP = 0, offN = 0;
        #pragma unroll
        for (int s = 0; s < CH / 64; ++s) {
            int idx = c * CH + s * 64 + lane;
            uint8_t f = (idx < NB) ? F[idx] : (uint8_t)0;
            bool p = (f & 1) != 0, n = (f & 2) != 0;
            unsigned long long mpm = __ballot(p), mnm = __ballot(n);
            unsigned long long lt = (1ULL << lane) - 1ULL;
            int rp = bp + offP + __popcll(mpm & lt);
            int rn = bn + offN + __popcll(mnm & lt);
            if (p && rp < numPos) selPos[rp] = idx;
            if (n && rn < numNeg) selNeg[rn] = idx;
            offP += __popcll(mpm); offN += __popcll(mnm);
        }
    }
    __syncthreads();

    float bce_acc = 0.0f, sl1_acc = 0.0f;
    for (int t = tid; t < numPos; t += 1024) {
        int i = selPos[t];
        float x = logits[(size_t)b * NB + i];
        bce_acc += fmaxf(x, 0.0f) - x + log1pf(expf(-fabsf(x)));
        float4 a = ((const float4*)anchors)[(size_t)b * NB + i];
        float a1 = (a.z - a.x) * (a.w - a.y);
        float ib = -1.0f, ub = 1.0f;
        int bi = 0;
        #pragma unroll 8
        for (int g = 0; g < GG; ++g) {
            float4 c = sG[g];
            float ga = (c.z - c.x) * (c.w - c.y);
            float w = fmaxf(fminf(a.z, c.z) - fmaxf(a.x, c.x), 0.0f);
            float h = fmaxf(fminf(a.w, c.w) - fmaxf(a.y, c.y), 0.0f);
            float inter = w * h;
            float u = (a1 + ga) - inter;
            bool better = inter * ub > ib * u;
            ib = better ? inter : ib;
            ub = better ? u : ub;
            bi = better ? g : bi;
        }
        float4 t4 = sG[bi];
        float acx = (a.x + a.z) / 2.0f, acy = (a.y + a.w) / 2.0f;
        float aw = a.z - a.x, ah = a.w - a.y;
        float tcx = (t4.x + t4.z) / 2.0f, tcy = (t4.y + t4.w) / 2.0f;
        float tw = t4.z - t4.x, th = t4.w - t4.y;
        float d0 = (tcx - acx) / aw;
        float d1 = (tcy - acy) / ah;
        float d2 = logf(tw / aw);
        float d3 = logf(th / ah);
        float4 r = ((const float4*)breg)[(size_t)b * NB + i];
        float df;
        df = fabsf(r.x - d0); sl1_acc += (df < 1.0f) ? 0.5f * df * df : df - 0.5f;
        df = fabsf(r.y - d1); sl1_acc += (df < 1.0f) ? 0.5f * df * df : df - 0.5f;
        df = fabsf(r.z - d2); sl1_acc += (df < 1.0f) ? 0.5f * df * df : df - 0.5f;
        df = fabsf(r.w - d3); sl1_acc += (df < 1.0f) ? 0.5f * df * df : df - 0.5f;
    }
    for (int t = tid; t < numNeg; t += 1024) {
        int i = selNeg[t];
        float x = logits[(size_t)b * NB + i];
        bce_acc += fmaxf(x, 0.0f) + log1pf(expf(-fabsf(x)));
    }
    for (int off = 32; off > 0; off >>= 1) {
        bce_acc += __shfl_down(bce_acc, off);
        sl1_acc += __shfl_down(sl1_acc, off);
    }
    if (lane == 0) {
        atomicAdd(&sB, bce_acc);
        atomicAdd(&sS, sl1_acc);
    }
    __syncthreads();
    if (tid == 0) {
        partial[b * 4 + 0] = sB;
        partial[b * 4 + 1] = (float)(numPos + numNeg);
        partial[b * 4 + 2] = sS;
        partial[b * 4 + 3] = (float)numPos;
    }
}

// ---------------- K3: finalize ----------------
__global__ void rpn_finalize_kernel(const float* __restrict__ partial, float* __restrict__ out) {
    float bce = 0.0f, val = 0.0f, sl1 = 0.0f, np = 0.0f;
    for (int b = 0; b < BB; ++b) {
        bce += partial[b * 4 + 0];
        val += partial[b * 4 + 1];
        sl1 += partial[b * 4 + 2];
        np  += partial[b * 4 + 3];
    }
    out[0] = bce / fmaxf(val, 1.0f);
    out[1] = sl1 / fmaxf(np * 4.0f, 1.0f);
}

extern "C" void kernel_launch(void* const* d_in, const int* in_sizes, int n_in,
                              void* d_out, int out_size, void* d_ws, size_t ws_size,
                              hipStream_t stream) {
    const float* cls  = (const float*)d_in[0];  // [B,N,1]
    const float* breg = (const float*)d_in[1];  // [B,N,4]
    const float* anch = (const float*)d_in[2];  // [B,N,4]
    const float* gt   = (const float*)d_in[3];  // [B,G,4]
    float* out = (float*)d_out;

    uint8_t*  flags    = (uint8_t*)d_ws;                            // B*N
    uint32_t* chunkCnt = (uint32_t*)((uint8_t*)d_ws + 800000);      // B*NCH
    float*    partial  = (float*)((uint8_t*)d_ws + 800000 + BB * NCH * 4);

    dim3 g1(NCH, BB);
    // real pipeline (r4 config)
    rpn_flags_kernel<<<g1, 256, 0, stream>>>(anch, gt, flags, chunkCnt);
    rpn_select_kernel<<<BB, 1024, 0, stream>>>(flags, cls, breg, anch, gt,
                                               chunkCnt, partial);
    rpn_finalize_kernel<<<1, 1, 0, stream>>>(partial, out);
    // probes (after consumption; flags/chunkCnt are fully rewritten by K1 each replay)
    rpn_probe_full<<<g1, 256, 0, stream>>>(anch, gt, flags, chunkCnt);
    rpn_probe_cmp<<<g1, 256, 0, stream>>>(gt, flags, chunkCnt);
    rpn_probe_mem<<<g1, 256, 0, stream>>>(anch, gt, flags, chunkCnt);
}

// Round 9
// 41.891 us; speedup vs baseline: 4.9213x; 4.9213x over previous
//
#include <hip/hip_runtime.h>
#include <stdint.h>

#define NB 200000
#define BB 4
#define GG 64
#define MAXPOS 128
#define BATCH 256
#define KPT 2                      // anchors per thread in K1 (packed into v2f)
#define CH 512                     // anchors per K1 block (256 thr * KPT)
#define NCH ((NB + CH - 1) / CH)   // 391

// thresholds folded: inter - t*u >= 0  <=>  ((1+t)/t)*inter - (a1+ga) >= 0
#define CP (1.7f / 0.7f)
#define CN (1.3f / 0.3f)

typedef float v2f __attribute__((ext_vector_type(2)));

static __device__ __forceinline__ v2f splat2(float s) { v2f r; r.x = s; r.y = s; return r; }

// ---------------- K1: packed-fp32 per-anchor threshold flags + per-chunk counts ----------------
// Two anchors per thread packed into v2f lanes -> v_pk_*_f32 (half the VALU issue).
// GT coords in LDS float4; one broadcast ds_read_b128 per g.
__global__ __launch_bounds__(256) void rpn_flags_kernel(
        const float* __restrict__ anchors, const float* __restrict__ gt,
        uint8_t* __restrict__ flags, uint32_t* __restrict__ chunkCnt) {
    int b = blockIdx.y;
    int tid = threadIdx.x, lane = tid & 63, wid = tid >> 6;
    __shared__ __align__(16) float4 sG[GG];
    if (tid < GG) sG[tid] = ((const float4*)gt)[b * GG + tid];
    __syncthreads();

    int base = blockIdx.x * CH + tid;          // k=0; k=1 strides by 256
    int i0 = base, i1 = base + 256;
    float4 A0 = (i0 < NB) ? ((const float4*)anchors)[(size_t)b * NB + i0]
                          : make_float4(0.f, 0.f, 0.f, 0.f);
    float4 A1 = (i1 < NB) ? ((const float4*)anchors)[(size_t)b * NB + i1]
                          : make_float4(0.f, 0.f, 0.f, 0.f);
    v2f ax; ax.x = A0.x; ax.y = A1.x;
    v2f ay; ay.x = A0.y; ay.y = A1.y;
    v2f az; az.x = A0.z; az.y = A1.z;
    v2f aw; aw.x = A0.w; aw.y = A1.w;
    v2f na1 = -((az - ax) * (aw - ay));
    v2f mp = splat2(-1.0f), mn = splat2(-1.0f);
    const v2f zero = splat2(0.0f);
    const v2f cp = splat2(CP), cn = splat2(CN);

    #pragma unroll 8
    for (int g = 0; g < GG; ++g) {
        float4 c = sG[g];                       // broadcast ds_read_b128
        float ga = (c.z - c.x) * (c.w - c.y);   // shared scalar
        v2f w = __builtin_elementwise_min(az, splat2(c.z))
              - __builtin_elementwise_max(ax, splat2(c.x));
        v2f h = __builtin_elementwise_min(aw, splat2(c.w))
              - __builtin_elementwise_max(ay, splat2(c.y));
        w = __builtin_elementwise_max(w, zero);
        h = __builtin_elementwise_max(h, zero);
        v2f inter = w * h;
        v2f ns = na1 - splat2(ga);
        mp = __builtin_elementwise_max(mp, __builtin_elementwise_fma(cp, inter, ns));
        mn = __builtin_elementwise_max(mn, __builtin_elementwise_fma(cn, inter, ns));
    }

    bool v0 = i0 < NB, v1 = i1 < NB;
    bool p0 = v0 && (mp.x >= 0.0f), n0 = v0 && (mn.x < 0.0f);
    bool p1 = v1 && (mp.y >= 0.0f), n1 = v1 && (mn.y < 0.0f);
    if (v0) flags[(size_t)b * NB + i0] = (uint8_t)((p0 ? 1 : 0) | (n0 ? 2 : 0));
    if (v1) flags[(size_t)b * NB + i1] = (uint8_t)((p1 ? 1 : 0) | (n1 ? 2 : 0));

    uint32_t pn = (p0 ? 1u : 0u) + (p1 ? 1u : 0u)
                + (n0 ? 0x10000u : 0u) + (n1 ? 0x10000u : 0u);
    for (int off = 32; off > 0; off >>= 1) pn += __shfl_down(pn, off);
    __shared__ uint32_t wSum[4];
    if (lane == 0) wSum[wid] = pn;
    __syncthreads();
    if (tid == 0)
        chunkCnt[b * NCH + blockIdx.x] = wSum[0] + wSum[1] + wSum[2] + wSum[3];
}

// ---------------- K2: scan chunk counts, parallel ordered selection, loss ----------------
__global__ __launch_bounds__(1024) void rpn_select_kernel(
        const uint8_t* __restrict__ flags,
        const float* __restrict__ logits, const float* __restrict__ breg,
        const float* __restrict__ anchors, const float* __restrict__ gt,
        const uint32_t* __restrict__ chunkCnt,
        float* __restrict__ partial) {
    int b = blockIdx.x;
    const uint8_t* __restrict__ F = flags + (size_t)b * NB;
    __shared__ __align__(16) float4 sG[GG];
    __shared__ int basP[NCH], basN[NCH];
    __shared__ unsigned long long wTot[16];
    __shared__ int sNumPos, sNumNeg;
    __shared__ int selPos[MAXPOS];
    __shared__ int selNeg[BATCH];
    __shared__ float sB, sS;
    int tid = threadIdx.x, lane = tid & 63, wid = tid >> 6;

    if (tid < GG) sG[tid] = ((const float4*)gt)[b * GG + tid];

    unsigned long long e = 0ULL;
    if (tid < NCH) {
        uint32_t c = chunkCnt[b * NCH + tid];
        e = (unsigned long long)(c & 0xFFFFu) | ((unsigned long long)(c >> 16) << 32);
    }
    unsigned long long inc = e;
    for (int off = 1; off < 64; off <<= 1) {
        unsigned long long v = __shfl_up(inc, off);
        if (lane >= off) inc += v;
    }
    if (lane == 63) wTot[wid] = inc;
    if (tid == 0) { sB = 0.0f; sS = 0.0f; }
    __syncthreads();
    if (wid == 0) {
        unsigned long long w = (lane < 16) ? wTot[lane] : 0ULL;
        unsigned long long winc = w;
        for (int off = 1; off < 16; off <<= 1) {
            unsigned long long v = __shfl_up(winc, off);
            if (lane >= off) winc += v;
        }
        if (lane < 16) wTot[lane] = winc - w;
        if (lane == 15) {
            int tp = (int)(winc & 0xFFFFFFFFULL);
            int tn = (int)(winc >> 32);
            int np_ = min(tp, MAXPOS);
            sNumPos = np_;
            sNumNeg = min(tn, BATCH - np_);
        }
    }
    __syncthreads();
    if (tid < NCH) {
        unsigned long long ex = wTot[wid] + (inc - e);
        basP[tid] = (int)(ex & 0xFFFFFFFFULL);
        basN[tid] = (int)(ex >> 32);
    }
    __syncthreads();
    int numPos = sNumPos, numNeg = sNumNeg;

    for (int c = wid; c < NCH; c += 16) {
        int bp = basP[c], bn = basN[c];
        if (bp >= numPos && bn >= numNeg) break;
        int offP = 0, offN = 0;
        #pragma unroll
        for (int s = 0; s < CH / 64; ++s) {
            int idx = c * CH + s * 64 + lane;
            uint8_t f = (idx < NB) ? F[idx] : (uint8_t)0;
            bool p = (f & 1) != 0, n = (f & 2) != 0;
            unsigned long long mpm = __ballot(p), mnm = __ballot(n);
            unsigned long long lt = (1ULL << lane) - 1ULL;
            int rp = bp + offP + __popcll(mpm & lt);
            int rn = bn + offN + __popcll(mnm & lt);
            if (p && rp < numPos) selPos[rp] = idx;
            if (n && rn < numNeg) selNeg[rn] = idx;
            offP += __popcll(mpm); offN += __popcll(mnm);
        }
    }
    __syncthreads();

    float bce_acc = 0.0f, sl1_acc = 0.0f;
    for (int t = tid; t < numPos; t += 1024) {
        int i = selPos[t];
        float x = logits[(size_t)b * NB + i];
        bce_acc += fmaxf(x, 0.0f) - x + log1pf(expf(-fabsf(x)));
        float4 a = ((const float4*)anchors)[(size_t)b * NB + i];
        float a1 = (a.z - a.x) * (a.w - a.y);
        float ib = -1.0f, ub = 1.0f;
        int bi = 0;
        #pragma unroll 8
        for (int g = 0; g < GG; ++g) {
            float4 c = sG[g];
            float ga = (c.z - c.x) * (c.w - c.y);
            float w = fmaxf(fminf(a.z, c.z) - fmaxf(a.x, c.x), 0.0f);
            float h = fmaxf(fminf(a.w, c.w) - fmaxf(a.y, c.y), 0.0f);
            float inter = w * h;
            float u = (a1 + ga) - inter;
            bool better = inter * ub > ib * u;
            ib = better ? inter : ib;
            ub = better ? u : ub;
            bi = better ? g : bi;
        }
        float4 t4 = sG[bi];
        float acx = (a.x + a.z) / 2.0f, acy = (a.y + a.w) / 2.0f;
        float aw = a.z - a.x, ah = a.w - a.y;
        float tcx = (t4.x + t4.z) / 2.0f, tcy = (t4.y + t4.w) / 2.0f;
        float tw = t4.z - t4.x, th = t4.w - t4.y;
        float d0 = (tcx - acx) / aw;
        float d1 = (tcy - acy) / ah;
        float d2 = logf(tw / aw);
        float d3 = logf(th / ah);
        float4 r = ((const float4*)breg)[(size_t)b * NB + i];
        float df;
        df = fabsf(r.x - d0); sl1_acc += (df < 1.0f) ? 0.5f * df * df : df - 0.5f;
        df = fabsf(r.y - d1); sl1_acc += (df < 1.0f) ? 0.5f * df * df : df - 0.5f;
        df = fabsf(r.z - d2); sl1_acc += (df < 1.0f) ? 0.5f * df * df : df - 0.5f;
        df = fabsf(r.w - d3); sl1_acc += (df < 1.0f) ? 0.5f * df * df : df - 0.5f;
    }
    for (int t = tid; t < numNeg; t += 1024) {
        int i = selNeg[t];
        float x = logits[(size_t)b * NB + i];
        bce_acc += fmaxf(x, 0.0f) + log1pf(expf(-fabsf(x)));
    }
    for (int off = 32; off > 0; off >>= 1) {
        bce_acc += __shfl_down(bce_acc, off);
        sl1_acc += __shfl_down(sl1_acc, off);
    }
    if (lane == 0) {
        atomicAdd(&sB, bce_acc);
        atomicAdd(&sS, sl1_acc);
    }
    __syncthreads();
    if (tid == 0) {
        partial[b * 4 + 0] = sB;
        partial[b * 4 + 1] = (float)(numPos + numNeg);
        partial[b * 4 + 2] = sS;
        partial[b * 4 + 3] = (float)numPos;
    }
}

// ---------------- K3: finalize ----------------
__global__ void rpn_finalize_kernel(const float* __restrict__ partial, float* __restrict__ out) {
    float bce = 0.0f, val = 0.0f, sl1 = 0.0f, np = 0.0f;
    for (int b = 0; b < BB; ++b) {
        bce += partial[b * 4 + 0];
        val += partial[b * 4 + 1];
        sl1 += partial[b * 4 + 2];
        np  += partial[b * 4 + 3];
    }
    out[0] = bce / fmaxf(val, 1.0f);
    out[1] = sl1 / fmaxf(np * 4.0f, 1.0f);
}

extern "C" void kernel_launch(void* const* d_in, const int* in_sizes, int n_in,
                              void* d_out, int out_size, void* d_ws, size_t ws_size,
                              hipStream_t stream) {
    const float* cls  = (const float*)d_in[0];  // [B,N,1]
    const float* breg = (const float*)d_in[1];  // [B,N,4]
    const float* anch = (const float*)d_in[2];  // [B,N,4]
    const float* gt   = (const float*)d_in[3];  // [B,G,4]
    float* out = (float*)d_out;

    uint8_t*  flags    = (uint8_t*)d_ws;                            // B*N
    uint32_t* chunkCnt = (uint32_t*)((uint8_t*)d_ws + 800000);      // B*NCH
    float*    partial  = (float*)((uint8_t*)d_ws + 800000 + BB * NCH * 4);

    dim3 g1(NCH, BB);
    rpn_flags_kernel<<<g1, 256, 0, stream>>>(anch, gt, flags, chunkCnt);
    rpn_select_kernel<<<BB, 1024, 0, stream>>>(flags, cls, breg, anch, gt,
                                               chunkCnt, partial);
    rpn_finalize_kernel<<<1, 1, 0, stream>>>(partial, out);
}